// Round 5
// baseline (566.091 us; speedup 1.0000x reference)
//
#include <hip/hip_runtime.h>
#include <hip/hip_bf16.h>

// MoE layer: B=2,S=2048,D=1024,F=4096,E=8,K=2. T=4096 tokens.
// R5: 256-row 8-wave BK=64 grouped bf16 MFMA GEMM with T2 LDS XOR-swizzle
// (pre-swizzled global src for global_load_lds + swizzled ds_read),
// double-buffer, counted vmcnt, setprio, XCD-bijective block swizzle.
// GEMM1: 256x256 tile; GEMM2: 256x128 tile, full K=4096.

#define T_TOK 4096
#define D_DIM 1024
#define F_DIM 4096
#define E_NUM 8
#define CAP_ROWS 10240         // 8192 + 8*256 padding headroom
#define N_TILES (CAP_ROWS/256) // 40

typedef __attribute__((ext_vector_type(8))) short short8v;
typedef __attribute__((ext_vector_type(8))) unsigned short ushort8v;
typedef __attribute__((ext_vector_type(4))) float f32x4;

static __device__ __forceinline__ unsigned short f2bf(float f){
  union { float f; unsigned u; } v; v.f = f;
  unsigned r = (v.u + 0x7fffu + ((v.u >> 16) & 1u)) >> 16;  // RNE
  return (unsigned short)r;
}
static __device__ __forceinline__ float bf2f(unsigned short s){
  union { unsigned u; float f; } v; v.u = ((unsigned)s) << 16;
  return v.f;
}

static __device__ __forceinline__ void gload16(const void* g, void* l) {
  __builtin_amdgcn_global_load_lds(
      (const __attribute__((address_space(1))) unsigned int*)g,
      (__attribute__((address_space(3))) unsigned int*)l, 16, 0, 0);
}

__global__ __launch_bounds__(256) void k_init(int* counts, int* cursor,
                                              int* rows_token, float* rows_w){
  const int gid = blockIdx.x * 256 + threadIdx.x;
  if (gid < E_NUM) counts[gid] = 0;
  else if (gid < 2*E_NUM) cursor[gid - E_NUM] = 0;
  if (gid < CAP_ROWS) { rows_token[gid] = 0; rows_w[gid] = 0.f; }  // safe pads
}

// one wave per token: fp32 logits -> softmax -> probs + top-2; also emits xbf
__global__ __launch_bounds__(256) void k_router(
    const float* __restrict__ x, const float* __restrict__ Wr,
    const float* __restrict__ br, float* __restrict__ probs_out,
    int* __restrict__ topi, float* __restrict__ topw, int* __restrict__ counts,
    unsigned short* __restrict__ xbf)
{
  const int lane = threadIdx.x & 63;
  const int t = blockIdx.x * 4 + (threadIdx.x >> 6);
  float xv[16];
  #pragma unroll
  for (int i = 0; i < 16; ++i) xv[i] = x[(size_t)t*D_DIM + i*64 + lane];
  #pragma unroll
  for (int i = 0; i < 16; ++i) xbf[(size_t)t*D_DIM + i*64 + lane] = f2bf(xv[i]);
  float pe[E_NUM];
  #pragma unroll
  for (int e = 0; e < E_NUM; ++e) {
    float p = 0.f;
    #pragma unroll
    for (int i = 0; i < 16; ++i) p += xv[i] * Wr[(i*64 + lane)*E_NUM + e];
    #pragma unroll
    for (int off = 32; off >= 1; off >>= 1) p += __shfl_xor(p, off);
    pe[e] = p + br[e];
  }
  float m = pe[0];
  #pragma unroll
  for (int e = 1; e < E_NUM; ++e) m = fmaxf(m, pe[e]);
  float s = 0.f;
  #pragma unroll
  for (int e = 0; e < E_NUM; ++e) { pe[e] = expf(pe[e] - m); s += pe[e]; }
  const float inv = 1.f / s;
  int e1 = 0; float v1 = pe[0];
  #pragma unroll
  for (int e = 1; e < E_NUM; ++e) if (pe[e] > v1) { v1 = pe[e]; e1 = e; }
  int e2 = (e1 == 0) ? 1 : 0; float v2 = pe[e2];
  #pragma unroll
  for (int e = 0; e < E_NUM; ++e) if (e != e1 && pe[e] > v2) { v2 = pe[e]; e2 = e; }
  if (lane == 0) {
    #pragma unroll
    for (int e = 0; e < E_NUM; ++e) probs_out[(size_t)t*E_NUM + e] = pe[e] * inv;
    topi[t*2+0] = e1; topw[t*2+0] = v1 * inv;
    topi[t*2+1] = e2; topw[t*2+1] = v2 * inv;
    atomicAdd(&counts[e1], 1);
    atomicAdd(&counts[e2], 1);
  }
}

// serial scan: 256-padded per-expert bases + tile->expert map
__global__ void k_scan(const int* __restrict__ counts, int* __restrict__ pbase,
                       int* __restrict__ tile_e)
{
  if (threadIdx.x == 0 && blockIdx.x == 0) {
    int base = 0;
    for (int e = 0; e < E_NUM; ++e) {
      pbase[e] = base;
      const int nt = (counts[e] + 255) >> 8;
      for (int i = 0; i < nt; ++i) tile_e[(base >> 8) + i] = e;
      base += nt << 8;
    }
    pbase[E_NUM] = base;
    for (int tt = base >> 8; tt < N_TILES; ++tt) tile_e[tt] = -1;
  }
}

__global__ __launch_bounds__(256) void k_assign(
    const int* __restrict__ topi, const float* __restrict__ topw,
    const int* __restrict__ pbase, int* __restrict__ cursor,
    int* __restrict__ rows_token, float* __restrict__ rows_w,
    int* __restrict__ pair_of)
{
  const int t = blockIdx.x * 256 + threadIdx.x;
  if (t < T_TOK) {
    #pragma unroll
    for (int k = 0; k < 2; ++k) {
      const int e = topi[t*2+k];
      const int slot = atomicAdd(&cursor[e], 1);
      const int pid = pbase[e] + slot;
      rows_token[pid] = t;
      rows_w[pid] = topw[t*2+k];
      pair_of[t*2+k] = pid;
    }
  }
}

// transpose + convert: per expert, in fp32 [R][C] -> out bf16 [C][R]
template<int R, int C>
__global__ __launch_bounds__(256) void k_tcvt(const float* __restrict__ in,
                                              unsigned short* __restrict__ out)
{
  const size_t eo = (size_t)blockIdx.z * R * C;
  const int r0 = blockIdx.y * 64, c0 = blockIdx.x * 64;
  __shared__ unsigned short ls[64][66];
  const int t = threadIdx.x;
  const int rr = t >> 4, cc = (t & 15) * 4;
  #pragma unroll
  for (int p = 0; p < 4; ++p) {
    const float4 v = *(const float4*)&in[eo + (size_t)(r0 + p*16 + rr)*C + c0 + cc];
    ls[p*16+rr][cc+0]=f2bf(v.x); ls[p*16+rr][cc+1]=f2bf(v.y);
    ls[p*16+rr][cc+2]=f2bf(v.z); ls[p*16+rr][cc+3]=f2bf(v.w);
  }
  __syncthreads();
  const int kc = (t & 7) * 8, nn0 = t >> 3;
  #pragma unroll
  for (int p = 0; p < 2; ++p) {
    const int nn = nn0 + p*32;
    ushort8v o;
    #pragma unroll
    for (int j = 0; j < 8; ++j) o[j] = ls[kc + j][nn];
    *(ushort8v*)&out[eo + (size_t)(c0 + nn)*R + r0 + kc] = o;
  }
}

// grouped bf16 MFMA GEMM: BM=256, 8 waves (2Mx4N), BK=64, double-buffered,
// T2 swizzle, counted vmcnt, setprio. C[r,n] = sum_k A[r,k]*Bt[n,k].
// EPI 1: relu(acc+bias) -> h.  EPI 2: (acc+bias)*rows_w -> y.
template<int BN, bool GATHER, int NDIM, int KT, int EPI>
__global__ __launch_bounds__(512, 2) void k_gemm(
    const unsigned short* __restrict__ A,
    const unsigned short* __restrict__ Bt,   // per-expert [NDIM][KDIM] bf16
    const float* __restrict__ bias,          // [E][NDIM]
    const int* __restrict__ tile_e,
    const int* __restrict__ rows_token,
    const float* __restrict__ rows_w,
    unsigned short* __restrict__ outp)
{
  constexpr int KDIM = KT * 64;
  constexpr int NB = BN / 64;     // b-frags per wave (4 or 2)
  constexpr int NCB = BN / 32;    // B staging calls per wave (8 or 4)
  // XCD-bijective block swizzle (grid.x*grid.y % 8 == 0 by construction)
  const int tot = gridDim.x * gridDim.y;
  int flat = blockIdx.x * gridDim.y + blockIdx.y;
  flat = (flat & 7) * (tot >> 3) + (flat >> 3);
  const int bx = flat / gridDim.y;
  const int by = flat % gridDim.y;
  const int e = tile_e[by];
  if (e < 0) return;
  const int rt = by * 256;
  const int ntc = bx * BN;
  __shared__ __align__(16) unsigned short As[2 * 256 * 64];
  __shared__ __align__(16) unsigned short Bs[2 * BN * 64];
  const int tid = threadIdx.x;
  const int lane = tid & 63;
  const int w = tid >> 6;
  // staging: waves 0-3 -> A (8 calls x 8 rows), waves 4-7 -> B (NCB calls).
  // LDS dest is linear (base + lane*16); global chunk pre-swizzled: g = c ^ (row&7)
  const int lr = lane >> 3;            // row within 8-row group
  const int g  = (lane & 7) ^ lr;      // swizzled 16B-chunk index in the row
  const unsigned short* gsrc[8];
  unsigned soff[8];
  if (w < 4) {
    #pragma unroll
    for (int i = 0; i < 8; ++i) {
      const int rl = i*32 + w*8 + lr;
      const int rowidx = GATHER ? rows_token[rt + rl] : (rt + rl);
      gsrc[i] = A + (size_t)rowidx * KDIM + g*8;
      soff[i] = (unsigned)((i*32 + w*8) * 64);
    }
  } else {
    const unsigned short* Be = Bt + (size_t)e * NDIM * KDIM;
    #pragma unroll
    for (int i = 0; i < NCB; ++i) {
      const int rl = i*32 + (w-4)*8 + lr;
      gsrc[i] = Be + (size_t)(ntc + rl) * KDIM + g*8;
      soff[i] = (unsigned)((i*32 + (w-4)*8) * 64);
    }
  }
  const int wr = w >> 2, wc = w & 3;
  const int cl = lane & 15, rgb = lane >> 4;
  const int swz = cl & 7;
  f32x4 acc[8][NB] = {};

  // prologue: stage K-tiles 0,1 into buffers 0,1
  if (w < 4) {
    #pragma unroll
    for (int i = 0; i < 8; ++i) gload16(gsrc[i], As + soff[i]);
    #pragma unroll
    for (int i = 0; i < 8; ++i) gload16(gsrc[i] + 64, As + 256*64 + soff[i]);
    asm volatile("s_waitcnt vmcnt(8)" ::: "memory");
  } else {
    #pragma unroll
    for (int i = 0; i < NCB; ++i) gload16(gsrc[i], Bs + soff[i]);
    #pragma unroll
    for (int i = 0; i < NCB; ++i) gload16(gsrc[i] + 64, Bs + BN*64 + soff[i]);
    if constexpr (BN == 256) { asm volatile("s_waitcnt vmcnt(8)" ::: "memory"); }
    else                     { asm volatile("s_waitcnt vmcnt(4)" ::: "memory"); }
  }
  __builtin_amdgcn_s_barrier();
  __builtin_amdgcn_sched_barrier(0);

  for (int t = 0; t < KT; ++t) {
    const unsigned short* Ab = As + (t & 1) * (256*64);
    const unsigned short* Bb = Bs + (t & 1) * (BN*64);
    #pragma unroll
    for (int ks = 0; ks < 2; ++ks) {
      short8v a[8], b[NB];
      const int ch = ((ks*4 + rgb) ^ swz) * 8;
      #pragma unroll
      for (int m = 0; m < 8; ++m)
        a[m] = *(const short8v*)&Ab[(wr*128 + m*16 + cl) * 64 + ch];
      #pragma unroll
      for (int n = 0; n < NB; ++n)
        b[n] = *(const short8v*)&Bb[(wc*(BN/4) + n*16 + cl) * 64 + ch];
      __builtin_amdgcn_s_setprio(1);
      #pragma unroll
      for (int m = 0; m < 8; ++m)
        #pragma unroll
        for (int n = 0; n < NB; ++n)
          acc[m][n] = __builtin_amdgcn_mfma_f32_16x16x32_bf16(a[m], b[n], acc[m][n], 0, 0, 0);
      __builtin_amdgcn_s_setprio(0);
    }
    asm volatile("s_waitcnt lgkmcnt(0)" ::: "memory");
    __builtin_amdgcn_sched_barrier(0);
    __builtin_amdgcn_s_barrier();            // all reads of this buffer done
    __builtin_amdgcn_sched_barrier(0);
    if (t + 2 < KT) {                        // stage(t+2) -> buffer just freed
      const int ko = (t + 2) * 64;
      if (w < 4) {
        #pragma unroll
        for (int i = 0; i < 8; ++i) gload16(gsrc[i] + ko, As + (t&1)*(256*64) + soff[i]);
        asm volatile("s_waitcnt vmcnt(8)" ::: "memory");   // stage(t+1) landed
      } else {
        #pragma unroll
        for (int i = 0; i < NCB; ++i) gload16(gsrc[i] + ko, Bs + (t&1)*(BN*64) + soff[i]);
        if constexpr (BN == 256) { asm volatile("s_waitcnt vmcnt(8)" ::: "memory"); }
        else                     { asm volatile("s_waitcnt vmcnt(4)" ::: "memory"); }
      }
    } else {
      asm volatile("s_waitcnt vmcnt(0)" ::: "memory");     // tail drain
    }
    __builtin_amdgcn_s_barrier();            // stage(t+1) certified chip-wide
    __builtin_amdgcn_sched_barrier(0);
  }

  // epilogue: C/D layout col = lane&15, row = (lane>>4)*4 + reg  [m89]
  // pack bf16 pairs across lane^1 -> dword stores from even lanes
  const size_t ebias = (size_t)e * NDIM;
  #pragma unroll
  for (int m = 0; m < 8; ++m) {
    const int row = rt + wr*128 + m*16 + rgb*4;
    float4 rw4 = make_float4(0,0,0,0);
    if (EPI == 2) rw4 = *(const float4*)&rows_w[row];
    #pragma unroll
    for (int n = 0; n < NB; ++n) {
      const int col = ntc + wc*(BN/4) + n*16 + cl;
      const float bv = bias[ebias + col];
      #pragma unroll
      for (int r = 0; r < 4; ++r) {
        float v = acc[m][n][r] + bv;
        if (EPI == 1) v = fmaxf(v, 0.f);
        else          v *= ((const float*)&rw4)[r];
        const unsigned short hb = f2bf(v);
        const unsigned short ob = (unsigned short)__shfl_xor((int)(unsigned)hb, 1);
        if ((lane & 1) == 0) {
          *(unsigned*)&outp[(size_t)(row + r) * NDIM + col] =
              (unsigned)hb | ((unsigned)ob << 16);
        }
      }
    }
  }
}

// out[t] = y[pair0(t)] + y[pair1(t)]  (y bf16, fixed order -> deterministic)
__global__ __launch_bounds__(256) void k_combine(
    const unsigned short* __restrict__ y, const int* __restrict__ pair_of,
    float* __restrict__ out)
{
  const int gid = blockIdx.x * 256 + threadIdx.x;   // T*D/8 threads
  const int t = gid >> 7;
  const int c = (gid & 127) * 8;
  const int p0 = pair_of[t*2+0];
  const int p1 = pair_of[t*2+1];
  const ushort8v a = *(const ushort8v*)&y[(size_t)p0*D_DIM + c];
  const ushort8v b = *(const ushort8v*)&y[(size_t)p1*D_DIM + c];
  float o[8];
  #pragma unroll
  for (int j = 0; j < 8; ++j) o[j] = bf2f(a[j]) + bf2f(b[j]);
  float4 o0; o0.x=o[0]; o0.y=o[1]; o0.z=o[2]; o0.w=o[3];
  float4 o1; o1.x=o[4]; o1.y=o[5]; o1.z=o[6]; o1.w=o[7];
  *(float4*)&out[(size_t)t*D_DIM + c]     = o0;
  *(float4*)&out[(size_t)t*D_DIM + c + 4] = o1;
}

extern "C" void kernel_launch(void* const* d_in, const int* in_sizes, int n_in,
                              void* d_out, int out_size, void* d_ws, size_t ws_size,
                              hipStream_t stream)
{
  const float* x  = (const float*)d_in[0];
  const float* Wr = (const float*)d_in[1];
  const float* br = (const float*)d_in[2];
  const float* W1 = (const float*)d_in[3];
  const float* b1 = (const float*)d_in[4];
  const float* W2 = (const float*)d_in[5];
  const float* b2 = (const float*)d_in[6];
  (void)in_sizes; (void)n_in; (void)out_size; (void)ws_size;

  float* out   = (float*)d_out;
  float* probs = out + (size_t)T_TOK * D_DIM;

  char* w = (char*)d_ws;
  size_t off = 0;
  int*   counts     = (int*)(w + off); off += 256;
  int*   cursor     = (int*)(w + off); off += 256;
  int*   pbase      = (int*)(w + off); off += 512;
  int*   tile_e     = (int*)(w + off); off += 3072;
  int*   topi       = (int*)(w + off); off += (size_t)T_TOK*2*4;
  float* topw       = (float*)(w + off); off += (size_t)T_TOK*2*4;
  int*   pair_of    = (int*)(w + off); off += (size_t)T_TOK*2*4;
  int*   rows_token = (int*)(w + off); off += (size_t)CAP_ROWS*4;
  float* rows_w     = (float*)(w + off); off += (size_t)CAP_ROWS*4;
  off = (off + 255) & ~(size_t)255;
  unsigned short* xbf = (unsigned short*)(w + off); off += (size_t)T_TOK*D_DIM*2;
  unsigned short* Wt  = (unsigned short*)(w + off); off += (size_t)E_NUM*D_DIM*F_DIM*2;
  unsigned short* h   = (unsigned short*)(w + off); off += (size_t)CAP_ROWS*F_DIM*2;
  unsigned short* y   = (unsigned short*)(w + off); off += (size_t)CAP_ROWS*D_DIM*2;
  // total ~182 MB

  k_init<<<(CAP_ROWS + 255) / 256, 256, 0, stream>>>(counts, cursor, rows_token, rows_w);
  k_router<<<T_TOK / 4, 256, 0, stream>>>(x, Wr, br, probs, topi, topw, counts, xbf);
  k_scan<<<1, 64, 0, stream>>>(counts, pbase, tile_e);
  k_assign<<<T_TOK / 256, 256, 0, stream>>>(topi, topw, pbase, cursor,
                                            rows_token, rows_w, pair_of);
  // W1 [E][D][F] -> Wt [E][F][D] bf16
  k_tcvt<D_DIM, F_DIM><<<dim3(F_DIM/64, D_DIM/64, E_NUM), 256, 0, stream>>>(W1, Wt);
  k_gemm<256, true, F_DIM, 16, 1><<<dim3(F_DIM/256, N_TILES), 512, 0, stream>>>(
      xbf, Wt, b1, tile_e, rows_token, rows_w, h);
  // W2 [E][F][D] -> Wt [E][D][F] bf16 (overwrites W1t; stream-ordered)
  k_tcvt<F_DIM, D_DIM><<<dim3(D_DIM/64, F_DIM/64, E_NUM), 256, 0, stream>>>(W2, Wt);
  k_gemm<128, false, D_DIM, 64, 2><<<dim3(D_DIM/128, N_TILES), 512, 0, stream>>>(
      h, Wt, b2, tile_e, rows_token, rows_w, y);
  k_combine<<<T_TOK * D_DIM / 8 / 256, 256, 0, stream>>>(y, pair_of, out);
}

// Round 6
// 475.207 us; speedup vs baseline: 1.1913x; 1.1913x over previous
//
#include <hip/hip_runtime.h>
#include <hip/hip_bf16.h>

// MoE layer: B=2,S=2048,D=1024,F=4096,E=8,K=2. T=4096 tokens.
// R6: R4's proven GEMM (128x128, BK=32, 3-buf depth-2 prefetch, 1-barrier
// loop, counted vmcnt) + R5's proven XCD-bijective block swizzle with
// B-panel-major ordering (FETCH 340->116MB) + folded x-convert + parallel scan.

#define T_TOK 4096
#define D_DIM 1024
#define F_DIM 4096
#define E_NUM 8
#define CAP_ROWS 9216          // 8192 + 8*128 padding headroom
#define N_TILES (CAP_ROWS/128) // 72

typedef __attribute__((ext_vector_type(8))) short short8v;
typedef __attribute__((ext_vector_type(8))) unsigned short ushort8v;
typedef __attribute__((ext_vector_type(4))) float f32x4;

static __device__ __forceinline__ unsigned short f2bf(float f){
  union { float f; unsigned u; } v; v.f = f;
  unsigned r = (v.u + 0x7fffu + ((v.u >> 16) & 1u)) >> 16;  // RNE
  return (unsigned short)r;
}
static __device__ __forceinline__ float bf2f(unsigned short s){
  union { unsigned u; float f; } v; v.u = ((unsigned)s) << 16;
  return v.f;
}

static __device__ __forceinline__ void gload16(const void* g, void* l) {
  __builtin_amdgcn_global_load_lds(
      (const __attribute__((address_space(1))) unsigned int*)g,
      (__attribute__((address_space(3))) unsigned int*)l, 16, 0, 0);
}

__global__ __launch_bounds__(256) void k_init(int* counts, int* cursor,
                                              int* rows_token, float* rows_w){
  const int gid = blockIdx.x * 256 + threadIdx.x;
  if (gid < E_NUM) counts[gid] = 0;
  else if (gid < 2*E_NUM) cursor[gid - E_NUM] = 0;
  if (gid < CAP_ROWS) { rows_token[gid] = 0; rows_w[gid] = 0.f; }  // safe pads
}

// one wave per token: fp32 logits -> softmax -> probs + top-2; emits xbf too
__global__ __launch_bounds__(256) void k_router(
    const float* __restrict__ x, const float* __restrict__ Wr,
    const float* __restrict__ br, float* __restrict__ probs_out,
    int* __restrict__ topi, float* __restrict__ topw, int* __restrict__ counts,
    unsigned short* __restrict__ xbf)
{
  const int lane = threadIdx.x & 63;
  const int t = blockIdx.x * 4 + (threadIdx.x >> 6);
  float xv[16];
  #pragma unroll
  for (int i = 0; i < 16; ++i) xv[i] = x[(size_t)t*D_DIM + i*64 + lane];
  #pragma unroll
  for (int i = 0; i < 16; ++i) xbf[(size_t)t*D_DIM + i*64 + lane] = f2bf(xv[i]);
  float pe[E_NUM];
  #pragma unroll
  for (int e = 0; e < E_NUM; ++e) {
    float p = 0.f;
    #pragma unroll
    for (int i = 0; i < 16; ++i) p += xv[i] * Wr[(i*64 + lane)*E_NUM + e];
    #pragma unroll
    for (int off = 32; off >= 1; off >>= 1) p += __shfl_xor(p, off);
    pe[e] = p + br[e];
  }
  float m = pe[0];
  #pragma unroll
  for (int e = 1; e < E_NUM; ++e) m = fmaxf(m, pe[e]);
  float s = 0.f;
  #pragma unroll
  for (int e = 0; e < E_NUM; ++e) { pe[e] = expf(pe[e] - m); s += pe[e]; }
  const float inv = 1.f / s;
  int e1 = 0; float v1 = pe[0];
  #pragma unroll
  for (int e = 1; e < E_NUM; ++e) if (pe[e] > v1) { v1 = pe[e]; e1 = e; }
  int e2 = (e1 == 0) ? 1 : 0; float v2 = pe[e2];
  #pragma unroll
  for (int e = 0; e < E_NUM; ++e) if (e != e1 && pe[e] > v2) { v2 = pe[e]; e2 = e; }
  if (lane == 0) {
    #pragma unroll
    for (int e = 0; e < E_NUM; ++e) probs_out[(size_t)t*E_NUM + e] = pe[e] * inv;
    topi[t*2+0] = e1; topw[t*2+0] = v1 * inv;
    topi[t*2+1] = e2; topw[t*2+1] = v2 * inv;
    atomicAdd(&counts[e1], 1);
    atomicAdd(&counts[e2], 1);
  }
}

// parallel scan: 128-padded per-expert bases + tile->expert map (one block)
__global__ __launch_bounds__(256) void k_scan(
    const int* __restrict__ counts, int* __restrict__ pbase,
    int* __restrict__ tile_e)
{
  __shared__ int base_s[E_NUM + 1];
  const int tid = threadIdx.x;
  if (tid == 0) {
    int base = 0;
    #pragma unroll
    for (int e = 0; e < E_NUM; ++e) {
      base_s[e] = base;
      base += ((counts[e] + 127) >> 7) << 7;
    }
    base_s[E_NUM] = base;
  }
  __syncthreads();
  if (tid <= E_NUM) pbase[tid] = base_s[tid];
  if (tid < N_TILES) {
    const int r0 = tid << 7;
    int e = -1;
    #pragma unroll
    for (int k = 0; k < E_NUM; ++k)
      if (r0 >= base_s[k] && r0 < base_s[k+1]) e = k;
    tile_e[tid] = e;
  }
}

__global__ __launch_bounds__(256) void k_assign(
    const int* __restrict__ topi, const float* __restrict__ topw,
    const int* __restrict__ pbase, int* __restrict__ cursor,
    int* __restrict__ rows_token, float* __restrict__ rows_w,
    int* __restrict__ pair_of)
{
  const int t = blockIdx.x * 256 + threadIdx.x;
  if (t < T_TOK) {
    #pragma unroll
    for (int k = 0; k < 2; ++k) {
      const int e = topi[t*2+k];
      const int slot = atomicAdd(&cursor[e], 1);
      const int pid = pbase[e] + slot;
      rows_token[pid] = t;
      rows_w[pid] = topw[t*2+k];
      pair_of[t*2+k] = pid;
    }
  }
}

// transpose + convert: per expert, in fp32 [R][C] -> out bf16 [C][R]
template<int R, int C>
__global__ __launch_bounds__(256) void k_tcvt(const float* __restrict__ in,
                                              unsigned short* __restrict__ out)
{
  const size_t eo = (size_t)blockIdx.z * R * C;
  const int r0 = blockIdx.y * 64, c0 = blockIdx.x * 64;
  __shared__ unsigned short ls[64][66];
  const int t = threadIdx.x;
  const int rr = t >> 4, cc = (t & 15) * 4;
  #pragma unroll
  for (int p = 0; p < 4; ++p) {
    const float4 v = *(const float4*)&in[eo + (size_t)(r0 + p*16 + rr)*C + c0 + cc];
    ls[p*16+rr][cc+0]=f2bf(v.x); ls[p*16+rr][cc+1]=f2bf(v.y);
    ls[p*16+rr][cc+2]=f2bf(v.z); ls[p*16+rr][cc+3]=f2bf(v.w);
  }
  __syncthreads();
  const int kc = (t & 7) * 8, nn0 = t >> 3;
  #pragma unroll
  for (int p = 0; p < 2; ++p) {
    const int nn = nn0 + p*32;
    ushort8v o;
    #pragma unroll
    for (int j = 0; j < 8; ++j) o[j] = ls[kc + j][nn];
    *(ushort8v*)&out[eo + (size_t)(c0 + nn)*R + r0 + kc] = o;
  }
}

// grouped bf16 MFMA GEMM, pipelined: C[r,n] = sum_k A[r,k]*Bt[n,k]
// 3 LDS buffers, stage(t+2) in flight, vmcnt(4) certifies stage(t+1).
// XCD-bijective block swizzle: each XCD owns contiguous B-panel groups.
template<bool GATHER, int NDIM, int KDIM, bool EPI1>
__global__ __launch_bounds__(256, 2) void k_gemm(
    const unsigned short* __restrict__ A,
    const unsigned short* __restrict__ Bt,   // per-expert [NDIM][KDIM] bf16
    const float* __restrict__ bias,          // [E][NDIM]
    const int* __restrict__ tile_e,
    const int* __restrict__ rows_token,
    const float* __restrict__ rows_w,
    unsigned short* __restrict__ outp)
{
  // flat = bx*gridDim.y + by  (consecutive = same B-panel); XCD-chunked remap.
  // grid.x*grid.y % 8 == 0 by construction (72 row-tiles * {32,8} col-tiles).
  const int tot = gridDim.x * gridDim.y;
  int flat = blockIdx.x * gridDim.y + blockIdx.y;
  flat = (flat & 7) * (tot >> 3) + (flat >> 3);
  const int bx = flat / gridDim.y;
  const int by = flat % gridDim.y;
  const int e = tile_e[by];
  if (e < 0) return;
  const int rt = by * 128;
  const int ntc = bx * 128;
  // LB[buf][0]=A-tile, LB[buf][1]=B-tile; each 128 rows x 32 bf16 = 8KB
  __shared__ __align__(16) unsigned short LB[3][2][128*32];
  const int tid = threadIdx.x;
  const int lane = tid & 63;
  const int w = tid >> 6;
  const int seg = w & 1;
  const int isB = (w >= 2) ? 1 : 0;
  const int lrow = lane >> 2, lchunk = lane & 3;   // 16 rows x 4 chunks of 16B
  const unsigned short* gsrc[4];
  unsigned lds_off[4];
  if (w < 2) {
    #pragma unroll
    for (int i = 0; i < 4; ++i) {
      const int rl = seg*64 + i*16 + lrow;
      const int rowidx = GATHER ? rows_token[rt + rl] : (rt + rl);
      gsrc[i] = A + (size_t)rowidx * KDIM + lchunk*8;
      lds_off[i] = (unsigned)((seg*64 + i*16)*32);
    }
  } else {
    const unsigned short* Be = Bt + (size_t)e * NDIM * KDIM;
    #pragma unroll
    for (int i = 0; i < 4; ++i) {
      const int rl = seg*64 + i*16 + lrow;
      gsrc[i] = Be + (size_t)(ntc + rl) * KDIM + lchunk*8;
      lds_off[i] = (unsigned)((seg*64 + i*16)*32);
    }
  }
  const int wr = w >> 1, wc = w & 1;
  const int cl = lane & 15, rgb = lane >> 4;
  f32x4 acc[4][4] = {};

  constexpr int NT = KDIM / 32;
  // prologue: stage tiles 0,1 into buffers 0,1
  #pragma unroll
  for (int i = 0; i < 4; ++i) gload16(gsrc[i] + 0,  &LB[0][isB][lds_off[i]]);
  #pragma unroll
  for (int i = 0; i < 4; ++i) gload16(gsrc[i] + 32, &LB[1][isB][lds_off[i]]);
  asm volatile("s_waitcnt vmcnt(4)" ::: "memory");   // stage(0) landed (own)
  __builtin_amdgcn_s_barrier();                      // all waves certified

  int buf = 0;
  for (int t = 0; t < NT; ++t) {
    const int pb = (buf == 0) ? 2 : (buf - 1);       // (t+2)%3
    if (t + 2 < NT) {
      const int kof = (t + 2) * 32;
      #pragma unroll
      for (int i = 0; i < 4; ++i) gload16(gsrc[i] + kof, &LB[pb][isB][lds_off[i]]);
    }
    short8v a[4], b[4];
    #pragma unroll
    for (int m = 0; m < 4; ++m)
      a[m] = *(const short8v*)&LB[buf][0][(wr*64 + m*16 + cl)*32 + rgb*8];
    #pragma unroll
    for (int n = 0; n < 4; ++n)
      b[n] = *(const short8v*)&LB[buf][1][(wc*64 + n*16 + cl)*32 + rgb*8];
    #pragma unroll
    for (int m = 0; m < 4; ++m)
      #pragma unroll
      for (int n = 0; n < 4; ++n)
        acc[m][n] = __builtin_amdgcn_mfma_f32_16x16x32_bf16(a[m], b[n], acc[m][n], 0, 0, 0);
    if (t + 2 < NT) {
      asm volatile("s_waitcnt vmcnt(4)" ::: "memory"); // stage(t+1) landed
    } else {
      asm volatile("s_waitcnt vmcnt(0)" ::: "memory"); // tail: drain
    }
    __builtin_amdgcn_s_barrier();
    buf = (buf == 2) ? 0 : (buf + 1);
  }

  // epilogue: C/D layout col = lane&15, row = (lane>>4)*4 + reg  [m89]
  // pack bf16 pairs across lane^1 (cols col,col+1) -> dword stores, even lanes
  const size_t ebias = (size_t)e * NDIM;
  #pragma unroll
  for (int n = 0; n < 4; ++n) {
    const int col = ntc + wc*64 + n*16 + cl;
    const float bv = bias[ebias + col];
    #pragma unroll
    for (int m = 0; m < 4; ++m) {
      const int row = rt + wr*64 + m*16 + rgb*4;
      #pragma unroll
      for (int r = 0; r < 4; ++r) {
        float v = acc[m][n][r] + bv;
        if (EPI1) v = fmaxf(v, 0.f);
        else      v *= rows_w[row + r];
        const unsigned short hb = f2bf(v);
        const unsigned short ob = (unsigned short)__shfl_xor((int)(unsigned)hb, 1);
        if ((lane & 1) == 0) {
          const unsigned pk = (unsigned)hb | ((unsigned)ob << 16);
          *(unsigned*)&outp[(size_t)(row + r)*NDIM + col] = pk;
        }
      }
    }
  }
}

// out[t] = y[pair0(t)] + y[pair1(t)]  (y bf16, fixed order -> deterministic)
__global__ __launch_bounds__(256) void k_combine(
    const unsigned short* __restrict__ y, const int* __restrict__ pair_of,
    float* __restrict__ out)
{
  const int gid = blockIdx.x * 256 + threadIdx.x;   // T*D/8 threads
  const int t = gid >> 7;
  const int c = (gid & 127) * 8;
  const int p0 = pair_of[t*2+0];
  const int p1 = pair_of[t*2+1];
  const ushort8v a = *(const ushort8v*)&y[(size_t)p0*D_DIM + c];
  const ushort8v b = *(const ushort8v*)&y[(size_t)p1*D_DIM + c];
  float o[8];
  #pragma unroll
  for (int j = 0; j < 8; ++j) o[j] = bf2f(a[j]) + bf2f(b[j]);
  float4 o0; o0.x=o[0]; o0.y=o[1]; o0.z=o[2]; o0.w=o[3];
  float4 o1; o1.x=o[4]; o1.y=o[5]; o1.z=o[6]; o1.w=o[7];
  *(float4*)&out[(size_t)t*D_DIM + c]     = o0;
  *(float4*)&out[(size_t)t*D_DIM + c + 4] = o1;
}

extern "C" void kernel_launch(void* const* d_in, const int* in_sizes, int n_in,
                              void* d_out, int out_size, void* d_ws, size_t ws_size,
                              hipStream_t stream)
{
  const float* x  = (const float*)d_in[0];
  const float* Wr = (const float*)d_in[1];
  const float* br = (const float*)d_in[2];
  const float* W1 = (const float*)d_in[3];
  const float* b1 = (const float*)d_in[4];
  const float* W2 = (const float*)d_in[5];
  const float* b2 = (const float*)d_in[6];
  (void)in_sizes; (void)n_in; (void)out_size; (void)ws_size;

  float* out   = (float*)d_out;
  float* probs = out + (size_t)T_TOK * D_DIM;

  char* w = (char*)d_ws;
  size_t off = 0;
  int*   counts     = (int*)(w + off); off += 256;
  int*   cursor     = (int*)(w + off); off += 256;
  int*   pbase      = (int*)(w + off); off += 512;
  int*   tile_e     = (int*)(w + off); off += 3072;
  int*   topi       = (int*)(w + off); off += (size_t)T_TOK*2*4;
  float* topw       = (float*)(w + off); off += (size_t)T_TOK*2*4;
  int*   pair_of    = (int*)(w + off); off += (size_t)T_TOK*2*4;
  int*   rows_token = (int*)(w + off); off += (size_t)CAP_ROWS*4;
  float* rows_w     = (float*)(w + off); off += (size_t)CAP_ROWS*4;
  off = (off + 255) & ~(size_t)255;
  unsigned short* xbf = (unsigned short*)(w + off); off += (size_t)T_TOK*D_DIM*2;
  unsigned short* Wt  = (unsigned short*)(w + off); off += (size_t)E_NUM*D_DIM*F_DIM*2;
  unsigned short* h   = (unsigned short*)(w + off); off += (size_t)CAP_ROWS*F_DIM*2;
  unsigned short* y   = (unsigned short*)(w + off); off += (size_t)CAP_ROWS*D_DIM*2;
  // total ~167 MB

  k_init<<<(CAP_ROWS + 255) / 256, 256, 0, stream>>>(counts, cursor, rows_token, rows_w);
  k_router<<<T_TOK / 4, 256, 0, stream>>>(x, Wr, br, probs, topi, topw, counts, xbf);
  k_scan<<<1, 256, 0, stream>>>(counts, pbase, tile_e);
  k_assign<<<T_TOK / 256, 256, 0, stream>>>(topi, topw, pbase, cursor,
                                            rows_token, rows_w, pair_of);
  // W1 [E][D][F] -> Wt [E][F][D] bf16
  k_tcvt<D_DIM, F_DIM><<<dim3(F_DIM/64, D_DIM/64, E_NUM), 256, 0, stream>>>(W1, Wt);
  k_gemm<true, F_DIM, D_DIM, true><<<dim3(F_DIM/128, N_TILES), 256, 0, stream>>>(
      xbf, Wt, b1, tile_e, rows_token, rows_w, h);
  // W2 [E][F][D] -> Wt [E][D][F] bf16 (overwrites W1t; stream-ordered)
  k_tcvt<F_DIM, D_DIM><<<dim3(D_DIM/64, F_DIM/64, E_NUM), 256, 0, stream>>>(W2, Wt);
  k_gemm<false, D_DIM, F_DIM, false><<<dim3(D_DIM/128, N_TILES), 256, 0, stream>>>(
      h, Wt, b2, tile_e, rows_token, rows_w, y);
  k_combine<<<T_TOK * D_DIM / 8 / 256, 256, 0, stream>>>(y, pair_of, out);
}

// Round 7
// 456.828 us; speedup vs baseline: 1.2392x; 1.0402x over previous
//
#include <hip/hip_runtime.h>
#include <hip/hip_bf16.h>

// MoE layer: B=2,S=2048,D=1024,F=4096,E=8,K=2. T=4096 tokens.
// R7: 3-slot-ring phase-split grouped bf16 MFMA GEMM.
// BM=256,BN=128,BK=64, 8 waves (4Mx2N), LDS 3x48KB=144KB.
// Tile t: 2 phases x {ds_read, stage 3 calls of tile t+2, barrier,
// setprio+16 MFMA, [vmcnt(6) at tile end], barrier}. Ring distance 2
// => staging never aliases tiles being read. XOR swizzle (proven 0-conflict).

#define T_TOK 4096
#define D_DIM 1024
#define F_DIM 4096
#define E_NUM 8
#define CAP_ROWS 10240         // 8192 + 8*256 padding headroom
#define N_TILES (CAP_ROWS/256) // 40

typedef __attribute__((ext_vector_type(8))) short short8v;
typedef __attribute__((ext_vector_type(8))) unsigned short ushort8v;
typedef __attribute__((ext_vector_type(4))) float f32x4;

static __device__ __forceinline__ unsigned short f2bf(float f){
  union { float f; unsigned u; } v; v.f = f;
  unsigned r = (v.u + 0x7fffu + ((v.u >> 16) & 1u)) >> 16;  // RNE
  return (unsigned short)r;
}
static __device__ __forceinline__ float bf2f(unsigned short s){
  union { unsigned u; float f; } v; v.u = ((unsigned)s) << 16;
  return v.f;
}

static __device__ __forceinline__ void gload16(const void* g, void* l) {
  __builtin_amdgcn_global_load_lds(
      (const __attribute__((address_space(1))) unsigned int*)g,
      (__attribute__((address_space(3))) unsigned int*)l, 16, 0, 0);
}

__global__ __launch_bounds__(256) void k_init(int* counts, int* cursor,
                                              int* rows_token, float* rows_w){
  const int gid = blockIdx.x * 256 + threadIdx.x;
  if (gid < E_NUM) counts[gid] = 0;
  else if (gid < 2*E_NUM) cursor[gid - E_NUM] = 0;
  if (gid < CAP_ROWS) { rows_token[gid] = 0; rows_w[gid] = 0.f; }  // safe pads
}

// one wave per token: fp32 logits -> softmax -> probs + top-2; emits xbf too
__global__ __launch_bounds__(256) void k_router(
    const float* __restrict__ x, const float* __restrict__ Wr,
    const float* __restrict__ br, float* __restrict__ probs_out,
    int* __restrict__ topi, float* __restrict__ topw, int* __restrict__ counts,
    unsigned short* __restrict__ xbf)
{
  const int lane = threadIdx.x & 63;
  const int t = blockIdx.x * 4 + (threadIdx.x >> 6);
  float xv[16];
  #pragma unroll
  for (int i = 0; i < 16; ++i) xv[i] = x[(size_t)t*D_DIM + i*64 + lane];
  #pragma unroll
  for (int i = 0; i < 16; ++i) xbf[(size_t)t*D_DIM + i*64 + lane] = f2bf(xv[i]);
  float pe[E_NUM];
  #pragma unroll
  for (int e = 0; e < E_NUM; ++e) {
    float p = 0.f;
    #pragma unroll
    for (int i = 0; i < 16; ++i) p += xv[i] * Wr[(i*64 + lane)*E_NUM + e];
    #pragma unroll
    for (int off = 32; off >= 1; off >>= 1) p += __shfl_xor(p, off);
    pe[e] = p + br[e];
  }
  float m = pe[0];
  #pragma unroll
  for (int e = 1; e < E_NUM; ++e) m = fmaxf(m, pe[e]);
  float s = 0.f;
  #pragma unroll
  for (int e = 0; e < E_NUM; ++e) { pe[e] = expf(pe[e] - m); s += pe[e]; }
  const float inv = 1.f / s;
  int e1 = 0; float v1 = pe[0];
  #pragma unroll
  for (int e = 1; e < E_NUM; ++e) if (pe[e] > v1) { v1 = pe[e]; e1 = e; }
  int e2 = (e1 == 0) ? 1 : 0; float v2 = pe[e2];
  #pragma unroll
  for (int e = 0; e < E_NUM; ++e) if (e != e1 && pe[e] > v2) { v2 = pe[e]; e2 = e; }
  if (lane == 0) {
    #pragma unroll
    for (int e = 0; e < E_NUM; ++e) probs_out[(size_t)t*E_NUM + e] = pe[e] * inv;
    topi[t*2+0] = e1; topw[t*2+0] = v1 * inv;
    topi[t*2+1] = e2; topw[t*2+1] = v2 * inv;
    atomicAdd(&counts[e1], 1);
    atomicAdd(&counts[e2], 1);
  }
}

// scan: 256-padded per-expert bases + tile->expert map (one block)
__global__ __launch_bounds__(256) void k_scan(
    const int* __restrict__ counts, int* __restrict__ pbase,
    int* __restrict__ tile_e)
{
  __shared__ int base_s[E_NUM + 1];
  const int tid = threadIdx.x;
  if (tid == 0) {
    int base = 0;
    #pragma unroll
    for (int e = 0; e < E_NUM; ++e) {
      base_s[e] = base;
      base += ((counts[e] + 255) >> 8) << 8;
    }
    base_s[E_NUM] = base;
  }
  __syncthreads();
  if (tid <= E_NUM) pbase[tid] = base_s[tid];
  if (tid < N_TILES) {
    const int r0 = tid << 8;
    int e = -1;
    #pragma unroll
    for (int k = 0; k < E_NUM; ++k)
      if (r0 >= base_s[k] && r0 < base_s[k+1]) e = k;
    tile_e[tid] = e;
  }
}

__global__ __launch_bounds__(256) void k_assign(
    const int* __restrict__ topi, const float* __restrict__ topw,
    const int* __restrict__ pbase, int* __restrict__ cursor,
    int* __restrict__ rows_token, float* __restrict__ rows_w,
    int* __restrict__ pair_of)
{
  const int t = blockIdx.x * 256 + threadIdx.x;
  if (t < T_TOK) {
    #pragma unroll
    for (int k = 0; k < 2; ++k) {
      const int e = topi[t*2+k];
      const int slot = atomicAdd(&cursor[e], 1);
      const int pid = pbase[e] + slot;
      rows_token[pid] = t;
      rows_w[pid] = topw[t*2+k];
      pair_of[t*2+k] = pid;
    }
  }
}

// transpose + convert: per expert, fp32 [R][C] -> bf16 [C][R]; fp32 LDS pad 67
template<int R, int C>
__global__ __launch_bounds__(256) void k_tcvt(const float* __restrict__ in,
                                              unsigned short* __restrict__ out)
{
  const size_t eo = (size_t)blockIdx.z * R * C;
  const int r0 = blockIdx.y * 64, c0 = blockIdx.x * 64;
  __shared__ float ls[64][67];
  const int t = threadIdx.x;
  const int rr = t >> 4, cc = (t & 15) * 4;
  #pragma unroll
  for (int p = 0; p < 4; ++p) {
    const float4 v = *(const float4*)&in[eo + (size_t)(r0 + p*16 + rr)*C + c0 + cc];
    ls[p*16+rr][cc+0]=v.x; ls[p*16+rr][cc+1]=v.y;
    ls[p*16+rr][cc+2]=v.z; ls[p*16+rr][cc+3]=v.w;
  }
  __syncthreads();
  const int nn = t >> 2, seg = (t & 3) * 16;
  ushort8v o0, o1;
  #pragma unroll
  for (int j = 0; j < 8; ++j) o0[j] = f2bf(ls[seg + j][nn]);
  #pragma unroll
  for (int j = 0; j < 8; ++j) o1[j] = f2bf(ls[seg + 8 + j][nn]);
  *(ushort8v*)&out[eo + (size_t)(c0 + nn)*R + r0 + seg]     = o0;
  *(ushort8v*)&out[eo + (size_t)(c0 + nn)*R + r0 + seg + 8] = o1;
}

// grouped bf16 MFMA GEMM: BM=256, BN=128, BK=64, 8 waves (4Mx2N),
// 3-slot LDS ring, 2 phases/tile, counted vmcnt(6), setprio.
// C[r,n] = sum_k A[r,k]*Bt[n,k].  EPI 1: relu+bias -> h. EPI 2: (acc+b)*w -> y.
template<bool GATHER, int NDIM, int NKT, int EPI>
__global__ __launch_bounds__(512) void k_gemm(
    const unsigned short* __restrict__ A,
    const unsigned short* __restrict__ Bt,   // per-expert [NDIM][KDIM] bf16
    const float* __restrict__ bias,          // [E][NDIM]
    const int* __restrict__ tile_e,
    const int* __restrict__ rows_token,
    const float* __restrict__ rows_w,
    unsigned short* __restrict__ outp)
{
  constexpr int KDIM = NKT * 64;
  // XCD-bijective swizzle, B-panel-major (proven FETCH cut)
  const int tot = gridDim.x * gridDim.y;
  int flat = blockIdx.x * gridDim.y + blockIdx.y;
  flat = (flat & 7) * (tot >> 3) + (flat >> 3);
  const int bx = flat / gridDim.y;
  const int by = flat % gridDim.y;
  const int e = tile_e[by];
  if (e < 0) return;
  const int rt = by * 256;
  const int ntc = bx * 128;
  // slot: rows 0-255 = A (256x64 bf16), rows 256-383 = B (128x64). 48KB/slot.
  __shared__ __align__(16) unsigned short LB[3][384 * 64];
  const int tid = threadIdx.x;
  const int lane = tid & 63;
  const int w = tid >> 6;
  // staging: 6 block-wide calls per tile (8KB each): c 0-3 = A rows c*64..,
  // c 4,5 = B rows (c-4)*64... ; thread row = (tid>>3), chunk pre-swizzled.
  const int trow = tid >> 3;                       // 0..63 within call
  const int g = (tid & 7) ^ (trow & 7);            // swizzled 16B-chunk
  const unsigned short* gp[6];
  unsigned lbase[6];
  #pragma unroll
  for (int c = 0; c < 4; ++c) {
    const int rl = c*64 + trow;
    const int rowidx = GATHER ? rows_token[rt + rl] : (rt + rl);
    gp[c] = A + (size_t)rowidx * KDIM + g*8;
    lbase[c] = (unsigned)((c*64 + w*8) * 64);
  }
  {
    const unsigned short* Be = Bt + (size_t)e * NDIM * KDIM;
    #pragma unroll
    for (int c = 4; c < 6; ++c) {
      const int rl = (c-4)*64 + trow;
      gp[c] = Be + (size_t)(ntc + rl) * KDIM + g*8;
      lbase[c] = (unsigned)((256 + (c-4)*64 + w*8) * 64);
    }
  }
  const int wr = w >> 1, wc = w & 1;               // 4M x 2N
  const int cl = lane & 15, rgb = lane >> 4;
  const int swz = cl & 7;
  f32x4 acc[4][4] = {};

  #define STAGE3(tt, c0_)                                            \
    { const int _s = (tt) % 3; const size_t _ko = (size_t)(tt) * 64; \
      gload16(gp[c0_+0] + _ko, &LB[_s][lbase[c0_+0]]);               \
      gload16(gp[c0_+1] + _ko, &LB[_s][lbase[c0_+1]]);               \
      gload16(gp[c0_+2] + _ko, &LB[_s][lbase[c0_+2]]); }

  // prologue: stage tiles 0,1 fully; certify tile 0 (6 in flight = tile 1)
  STAGE3(0, 0) STAGE3(0, 3)
  STAGE3(1, 0) STAGE3(1, 3)
  asm volatile("s_waitcnt vmcnt(6)" ::: "memory");
  __builtin_amdgcn_s_barrier();

  for (int t = 0; t < NKT; ++t) {
    const unsigned short* Sb = LB[t % 3];
    short8v b[4][2];
    // ---- phase 0: read a[m0,m1]+all b, stage first half of tile t+2 ----
    {
      short8v a[2][2];
      #pragma unroll
      for (int m = 0; m < 2; ++m)
        #pragma unroll
        for (int ks = 0; ks < 2; ++ks)
          a[m][ks] = *(const short8v*)&Sb[(wr*64 + m*16 + cl)*64 + ((ks*4+rgb)^swz)*8];
      #pragma unroll
      for (int n = 0; n < 4; ++n)
        #pragma unroll
        for (int ks = 0; ks < 2; ++ks)
          b[n][ks] = *(const short8v*)&Sb[(256 + wc*64 + n*16 + cl)*64 + ((ks*4+rgb)^swz)*8];
      if (t + 2 < NKT) STAGE3(t+2, 0)
      __builtin_amdgcn_s_barrier();
      __builtin_amdgcn_s_setprio(1);
      #pragma unroll
      for (int m = 0; m < 2; ++m)
        #pragma unroll
        for (int n = 0; n < 4; ++n)
          #pragma unroll
          for (int ks = 0; ks < 2; ++ks)
            acc[m][n] = __builtin_amdgcn_mfma_f32_16x16x32_bf16(a[m][ks], b[n][ks], acc[m][n], 0, 0, 0);
      __builtin_amdgcn_s_setprio(0);
      __builtin_amdgcn_s_barrier();
    }
    // ---- phase 1: read a[m2,m3] (b kept), stage second half, certify t+1 ----
    {
      short8v a[2][2];
      #pragma unroll
      for (int m = 0; m < 2; ++m)
        #pragma unroll
        for (int ks = 0; ks < 2; ++ks)
          a[m][ks] = *(const short8v*)&Sb[(wr*64 + (m+2)*16 + cl)*64 + ((ks*4+rgb)^swz)*8];
      if (t + 2 < NKT) STAGE3(t+2, 3)
      __builtin_amdgcn_s_barrier();
      __builtin_amdgcn_s_setprio(1);
      #pragma unroll
      for (int m = 0; m < 2; ++m)
        #pragma unroll
        for (int n = 0; n < 4; ++n)
          #pragma unroll
          for (int ks = 0; ks < 2; ++ks)
            acc[m+2][n] = __builtin_amdgcn_mfma_f32_16x16x32_bf16(a[m][ks], b[n][ks], acc[m+2][n], 0, 0, 0);
      __builtin_amdgcn_s_setprio(0);
      if (t + 1 < NKT) {
        if (t + 2 < NKT) { asm volatile("s_waitcnt vmcnt(6)" ::: "memory"); }
        else             { asm volatile("s_waitcnt vmcnt(0)" ::: "memory"); }
        __builtin_amdgcn_s_barrier();
      }
    }
  }
  #undef STAGE3

  // epilogue: C/D layout col = lane&15, row = (lane>>4)*4 + reg  [m89]
  // pack bf16 pairs across lane^1 -> dword stores from even lanes
  const size_t ebias = (size_t)e * NDIM;
  #pragma unroll
  for (int n = 0; n < 4; ++n) {
    const int col = ntc + wc*64 + n*16 + cl;
    const float bv = bias[ebias + col];
    #pragma unroll
    for (int m = 0; m < 4; ++m) {
      const int row = rt + wr*64 + m*16 + rgb*4;
      #pragma unroll
      for (int r = 0; r < 4; ++r) {
        float v = acc[m][n][r] + bv;
        if (EPI == 1) v = fmaxf(v, 0.f);
        else          v *= rows_w[row + r];
        const unsigned short hb = f2bf(v);
        const unsigned short ob = (unsigned short)__shfl_xor((int)(unsigned)hb, 1);
        if ((lane & 1) == 0) {
          const unsigned pk = (unsigned)hb | ((unsigned)ob << 16);
          *(unsigned*)&outp[(size_t)(row + r)*NDIM + col] = pk;
        }
      }
    }
  }
}

// out[t] = y[pair0(t)] + y[pair1(t)]  (y bf16, fixed order -> deterministic)
__global__ __launch_bounds__(256) void k_combine(
    const unsigned short* __restrict__ y, const int* __restrict__ pair_of,
    float* __restrict__ out)
{
  const int gid = blockIdx.x * 256 + threadIdx.x;   // T*D/8 threads
  const int t = gid >> 7;
  const int c = (gid & 127) * 8;
  const int p0 = pair_of[t*2+0];
  const int p1 = pair_of[t*2+1];
  const ushort8v a = *(const ushort8v*)&y[(size_t)p0*D_DIM + c];
  const ushort8v b = *(const ushort8v*)&y[(size_t)p1*D_DIM + c];
  float o[8];
  #pragma unroll
  for (int j = 0; j < 8; ++j) o[j] = bf2f(a[j]) + bf2f(b[j]);
  float4 o0; o0.x=o[0]; o0.y=o[1]; o0.z=o[2]; o0.w=o[3];
  float4 o1; o1.x=o[4]; o1.y=o[5]; o1.z=o[6]; o1.w=o[7];
  *(float4*)&out[(size_t)t*D_DIM + c]     = o0;
  *(float4*)&out[(size_t)t*D_DIM + c + 4] = o1;
}

extern "C" void kernel_launch(void* const* d_in, const int* in_sizes, int n_in,
                              void* d_out, int out_size, void* d_ws, size_t ws_size,
                              hipStream_t stream)
{
  const float* x  = (const float*)d_in[0];
  const float* Wr = (const float*)d_in[1];
  const float* br = (const float*)d_in[2];
  const float* W1 = (const float*)d_in[3];
  const float* b1 = (const float*)d_in[4];
  const float* W2 = (const float*)d_in[5];
  const float* b2 = (const float*)d_in[6];
  (void)in_sizes; (void)n_in; (void)out_size; (void)ws_size;

  float* out   = (float*)d_out;
  float* probs = out + (size_t)T_TOK * D_DIM;

  char* w = (char*)d_ws;
  size_t off = 0;
  int*   counts     = (int*)(w + off); off += 256;
  int*   cursor     = (int*)(w + off); off += 256;
  int*   pbase      = (int*)(w + off); off += 512;
  int*   tile_e     = (int*)(w + off); off += 3072;
  int*   topi       = (int*)(w + off); off += (size_t)T_TOK*2*4;
  float* topw       = (float*)(w + off); off += (size_t)T_TOK*2*4;
  int*   pair_of    = (int*)(w + off); off += (size_t)T_TOK*2*4;
  int*   rows_token = (int*)(w + off); off += (size_t)CAP_ROWS*4;
  float* rows_w     = (float*)(w + off); off += (size_t)CAP_ROWS*4;
  off = (off + 255) & ~(size_t)255;
  unsigned short* xbf = (unsigned short*)(w + off); off += (size_t)T_TOK*D_DIM*2;
  unsigned short* Wt  = (unsigned short*)(w + off); off += (size_t)E_NUM*D_DIM*F_DIM*2;
  unsigned short* h   = (unsigned short*)(w + off); off += (size_t)CAP_ROWS*F_DIM*2;
  unsigned short* y   = (unsigned short*)(w + off); off += (size_t)CAP_ROWS*D_DIM*2;
  // total ~180 MB

  k_init<<<(CAP_ROWS + 255) / 256, 256, 0, stream>>>(counts, cursor, rows_token, rows_w);
  k_router<<<T_TOK / 4, 256, 0, stream>>>(x, Wr, br, probs, topi, topw, counts, xbf);
  k_scan<<<1, 256, 0, stream>>>(counts, pbase, tile_e);
  k_assign<<<T_TOK / 256, 256, 0, stream>>>(topi, topw, pbase, cursor,
                                            rows_token, rows_w, pair_of);
  // W1 [E][D][F] -> Wt [E][F][D] bf16
  k_tcvt<D_DIM, F_DIM><<<dim3(F_DIM/64, D_DIM/64, E_NUM), 256, 0, stream>>>(W1, Wt);
  // GEMM1: M=CAP, N=F (32 panels), K=1024 (NKT=16)
  k_gemm<true, F_DIM, 16, 1><<<dim3(F_DIM/128, N_TILES), 512, 0, stream>>>(
      xbf, Wt, b1, tile_e, rows_token, rows_w, h);
  // W2 [E][F][D] -> Wt [E][D][F] bf16 (overwrites W1t; stream-ordered)
  k_tcvt<F_DIM, D_DIM><<<dim3(D_DIM/64, F_DIM/64, E_NUM), 256, 0, stream>>>(W2, Wt);
  // GEMM2: M=CAP, N=D (8 panels), K=4096 (NKT=64)
  k_gemm<false, D_DIM, 64, 2><<<dim3(D_DIM/128, N_TILES), 512, 0, stream>>>(
      h, Wt, b2, tile_e, rows_token, rows_w, y);
  k_combine<<<T_TOK * D_DIM / 8 / 256, 256, 0, stream>>>(y, pair_of, out);
}